// Round 9
// baseline (2995.064 us; speedup 1.0000x reference)
//
#include <hip/hip_runtime.h>
#include <hip/hip_fp16.h>

#define N_NODES 100000
#define D 128
#define N_ADJ 6
#define NNZ 600000
#define N_HOPS 7
#define EDGES_TOTAL (N_ADJ * NNZ)

#define SCAN_CHUNK 1024
#define SCAN_BLOCKS ((N_NODES + SCAN_CHUNK - 1) / SCAN_CHUNK)  // 98

#define B_SHIFT 7
#define B_ROWS 128
#define NB ((N_NODES + B_ROWS - 1) / B_ROWS)   // 782 buckets
#define CHUNK 4096                              // edges per passA workgroup
#define EPT 16                                  // edges per thread (CHUNK/256)

// Fixed bucket capacity: counts ~ Poisson(4608), sigma=68. CAP = mean+15sigma.
#define BCAP 5632

// Column segments for gather locality: 8192 nodes x 256B fp16 = 2MB < 4MB/XCD L2
#define SEG_SHIFT 13
#define NSEG 13                                 // ceil(100000 / 8192)
#define SEGP1 14
#define NBIN (NSEG * 2)                         // (seg, rowHalf) bins = 26
#define PULL_BLOCKS (NB * 2)                    // 1564 half-bucket blocks

// ---------------------------------------------------------------------------
// Phase 0: mix = softmax(linear_weight), 7 elements
// ---------------------------------------------------------------------------
__global__ void softmax_mix_kernel(const float* __restrict__ lw,
                                   float* __restrict__ mix) {
    if (threadIdx.x == 0) {
        float m = lw[0];
        for (int i = 1; i < N_HOPS; ++i) m = fmaxf(m, lw[i]);
        float e[N_HOPS];
        float s = 0.f;
        for (int i = 0; i < N_HOPS; ++i) { e[i] = __expf(lw[i] - m); s += e[i]; }
        float inv = 1.f / s;
        for (int i = 0; i < N_HOPS; ++i) mix[i] = e[i] * inv;
    }
}

// ---------------------------------------------------------------------------
// input (f32) -> input16 (fp16). 8 floats per thread, 16B stores.
// ---------------------------------------------------------------------------
__global__ __launch_bounds__(256) void conv16_kernel(
    const float4* __restrict__ in4, uint4* __restrict__ o16) {
    int i = blockIdx.x * 256 + threadIdx.x;
    if (i >= N_NODES * D / 8) return;
    float4 a = in4[2 * i];
    float4 b = in4[2 * i + 1];
    __half2 h0 = __floats2half2_rn(a.x, a.y);
    __half2 h1 = __floats2half2_rn(a.z, a.w);
    __half2 h2 = __floats2half2_rn(b.x, b.y);
    __half2 h3 = __floats2half2_rn(b.z, b.w);
    uint4 u;
    u.x = *reinterpret_cast<unsigned int*>(&h0);
    u.y = *reinterpret_cast<unsigned int*>(&h1);
    u.z = *reinterpret_cast<unsigned int*>(&h2);
    u.w = *reinterpret_cast<unsigned int*>(&h3);
    o16[i] = u;
}

// ---------------------------------------------------------------------------
// Middle/fallback path kernels (hist + scans + offsets pipeline)
// ---------------------------------------------------------------------------
__global__ __launch_bounds__(256) void hist_kernel(
    const int* __restrict__ rows, int* __restrict__ counts) {
    int e = blockIdx.x * 256 + threadIdx.x;
    if (e < EDGES_TOTAL) atomicAdd(&counts[rows[e]], 1);
}

__global__ __launch_bounds__(256) void scan_partial_kernel(
    const int* __restrict__ counts, int* __restrict__ blockSums) {
    __shared__ int lds[256];
    int base = blockIdx.x * SCAN_CHUNK;
    int t = threadIdx.x;
    int s = 0;
    #pragma unroll
    for (int k = 0; k < 4; ++k) {
        int i = base + t * 4 + k;
        s += (i < N_NODES) ? counts[i] : 0;
    }
    lds[t] = s;
    __syncthreads();
    for (int off = 128; off > 0; off >>= 1) {
        if (t < off) lds[t] += lds[t + off];
        __syncthreads();
    }
    if (t == 0) blockSums[blockIdx.x] = lds[0];
}

__global__ void scan_blocksums_kernel(int* __restrict__ blockSums) {
    if (threadIdx.x == 0) {
        int run = 0;
        for (int i = 0; i < SCAN_BLOCKS; ++i) {
            int c = blockSums[i];
            blockSums[i] = run;
            run += c;
        }
    }
}

__global__ __launch_bounds__(256) void scan_final_kernel(
    const int* __restrict__ counts, const int* __restrict__ blockSums,
    int* __restrict__ offsets) {
    __shared__ int lds[256];
    int base = blockIdx.x * SCAN_CHUNK;
    int t = threadIdx.x;
    int c[4];
    int s = 0;
    #pragma unroll
    for (int k = 0; k < 4; ++k) {
        int i = base + t * 4 + k;
        c[k] = (i < N_NODES) ? counts[i] : 0;
        s += c[k];
    }
    lds[t] = s;
    __syncthreads();
    for (int off = 1; off < 256; off <<= 1) {
        int u = 0;
        if (t >= off) u = lds[t - off];
        __syncthreads();
        if (t >= off) lds[t] += u;
        __syncthreads();
    }
    int texcl = lds[t] - s;
    int run = blockSums[blockIdx.x] + texcl;
    #pragma unroll
    for (int k = 0; k < 4; ++k) {
        int i = base + t * 4 + k;
        if (i < N_NODES) offsets[i] = run;
        run += c[k];
    }
    if (blockIdx.x == 0 && t == 0) offsets[N_NODES] = EDGES_TOTAL;
}

__global__ void bpos_init_kernel(const int* __restrict__ offsets,
                                 int* __restrict__ bpos) {
    int b = blockIdx.x * 256 + threadIdx.x;
    if (b < NB) bpos[b] = offsets[b << B_SHIFT];
}

__global__ void bpos_init_cap_kernel(int* __restrict__ bpos) {
    int b = blockIdx.x * 256 + threadIdx.x;
    if (b < NB) bpos[b] = b * BCAP;
}

// ---------------------------------------------------------------------------
// bbase scan: bucket counts from pass A cursors -> csr base per bucket.
// ---------------------------------------------------------------------------
__global__ void bbase_scan_kernel(const int* __restrict__ bpos,
                                  int* __restrict__ bbase) {
    if (threadIdx.x == 0) {
        int run = 0;
        for (int b = 0; b < NB; ++b) {
            bbase[b] = run;
            run += bpos[b] - b * BCAP;
        }
    }
}

// ---------------------------------------------------------------------------
// Pass A: LDS-aggregated bucket scatter (unchanged, r0 flush).
// ---------------------------------------------------------------------------
__global__ __launch_bounds__(256) void bucket_scatter_kernel(
    const int* __restrict__ rows, const int* __restrict__ cols,
    const float* __restrict__ vals, const float* __restrict__ mix,
    int* __restrict__ bpos, int2* __restrict__ tmp) {
    __shared__ int cnt[NB];
    __shared__ int off[NB];
    __shared__ int gbase[NB];
    __shared__ int scanbuf[256];
    __shared__ int2 stage[CHUNK];

    int base = blockIdx.x * CHUNK;
    int t = threadIdx.x;

    for (int i = t; i < NB; i += 256) cnt[i] = 0;
    __syncthreads();

    int myRow[EPT];
    int mySlot[EPT];
    #pragma unroll
    for (int k = 0; k < EPT; ++k) {
        int e = base + k * 256 + t;
        if (e < EDGES_TOTAL) {
            int r = rows[e];
            myRow[k] = r;
            mySlot[k] = atomicAdd(&cnt[r >> B_SHIFT], 1);
        } else {
            myRow[k] = -1;
            mySlot[k] = 0;
        }
    }
    __syncthreads();

    int i0 = t * 4;
    int c4[4];
    int s = 0;
    #pragma unroll
    for (int k = 0; k < 4; ++k) {
        int i = i0 + k;
        c4[k] = (i < NB) ? cnt[i] : 0;
        s += c4[k];
    }
    scanbuf[t] = s;
    __syncthreads();
    for (int o = 1; o < 256; o <<= 1) {
        int u = 0;
        if (t >= o) u = scanbuf[t - o];
        __syncthreads();
        if (t >= o) scanbuf[t] += u;
        __syncthreads();
    }
    int run = scanbuf[t] - s;
    #pragma unroll
    for (int k = 0; k < 4; ++k) {
        int i = i0 + k;
        if (i < NB) off[i] = run;
        run += c4[k];
    }
    for (int i = t; i < NB; i += 256)
        gbase[i] = atomicAdd(&bpos[i], cnt[i]);
    __syncthreads();

    #pragma unroll
    for (int k = 0; k < EPT; ++k) {
        int e = base + k * 256 + t;
        int r = myRow[k];
        if (r >= 0) {
            int b = r >> B_SHIFT;
            int rl = r & (B_ROWS - 1);
            int a = e / NNZ;
            float v = vals[e] * mix[a + 1];
            int packed = (rl << 25) | cols[e];
            stage[off[b] + mySlot[k]] = make_int2(packed, __float_as_int(v));
        }
    }
    __syncthreads();

    for (int i = t; i < NB; i += 256) {
        int c = cnt[i];
        int g = gbase[i];
        int o = off[i];
        for (int j = 0; j < c; ++j) tmp[g + j] = stage[o + j];
    }
}

// ---------------------------------------------------------------------------
// Pass B v4 (main path): bin each bucket's edges by (seg, rowHalf) = 26 bins.
// LDS-stages the window (single tmp read), counts 26 bins, prefix, emits
// bseg[b][27] boundaries, scatters to csr (edges keep full packed payload).
// Much cheaper than the per-(row,seg) version: 26 cursors vs 1664, no scans.
// ---------------------------------------------------------------------------
__global__ __launch_bounds__(256) void bucket_to_csr_binh_kernel(
    const int* __restrict__ bpos, const int2* __restrict__ tmp,
    const int* __restrict__ bbase, int2* __restrict__ csr,
    int* __restrict__ bseg) {
    __shared__ int2 stage[BCAP];        // 45KB
    __shared__ int bins[NBIN];
    __shared__ int binoff[NBIN + 1];
    int b = blockIdx.x;
    int t = threadIdx.x;
    int base = b * BCAP;
    int cnt = bpos[b] - base;

    if (t < NBIN) bins[t] = 0;
    __syncthreads();

    for (int j = t; j < cnt; j += 256) {
        int2 eo = tmp[base + j];
        stage[j] = eo;
        int col = eo.x & 0x01FFFFFF;
        int rl = ((unsigned)eo.x) >> 25;
        atomicAdd(&bins[(col >> SEG_SHIFT) * 2 + (rl >> 6)], 1);
    }
    __syncthreads();

    if (t == 0) {
        int run = bbase[b];
        #pragma unroll
        for (int i = 0; i < NBIN; ++i) { binoff[i] = run; run += bins[i]; }
        binoff[NBIN] = run;
    }
    __syncthreads();
    if (t < NBIN + 1) bseg[b * (NBIN + 1) + t] = binoff[t];
    if (t < NBIN) bins[t] = binoff[t];   // reuse as write cursors
    __syncthreads();

    for (int j = t; j < cnt; j += 256) {
        int2 eo = stage[j];
        int col = eo.x & 0x01FFFFFF;
        int rl = ((unsigned)eo.x) >> 25;
        int p = atomicAdd(&bins[(col >> SEG_SHIFT) * 2 + (rl >> 6)], 1);
        csr[p] = eo;
    }
}

// ---------------------------------------------------------------------------
// Pass B (plain, middle path): per-row cursors (r4 version).
// ---------------------------------------------------------------------------
__global__ __launch_bounds__(256) void bucket_to_csr_kernel(
    const int* __restrict__ offsets, const int2* __restrict__ tmp,
    int2* __restrict__ csr) {
    __shared__ int lpos[B_ROWS];
    int b = blockIdx.x;
    int rbase = b << B_SHIFT;
    int t = threadIdx.x;
    if (t < B_ROWS) {
        int r = rbase + t;
        lpos[t] = offsets[(r < N_NODES) ? r : N_NODES];
    }
    __syncthreads();
    int start = offsets[rbase];
    int endr = rbase + B_ROWS;
    int end = offsets[(endr < N_NODES) ? endr : N_NODES];
    for (int j = start + t; j < end; j += 256) {
        int2 eo = tmp[j];
        int rl = ((unsigned)eo.x) >> 25;
        int col = eo.x & 0x01FFFFFF;
        int p = atomicAdd(&lpos[rl], 1);
        csr[p] = make_int2(col, eo.y);
    }
}

// ---------------------------------------------------------------------------
// Pull v7 (edge-parallel, LDS accumulators): block = half-bucket (64 rows),
// acc[64][128] f32 in LDS (32KB -> 4 blocks/CU, 16 waves/CU). Per seg, the
// 4 waves split the (seg,h) bin range; ONE EDGE PER WAVE-ITERATION (unroll
// 4): lane l loads the 4B uint (2 halves) of input16[col], ds_add_f32 two
// floats into acc[rl&63][2l..2l+1] (bank 2l%32: 2-way aliasing = free).
// Kills r7's per-(row,seg) short-run divergence (wave trip = max of 4
// Poisson(2.8) runs) and the segoff dependent-load chain; csr reads become
// sequential. Seg-sweep L2 locality preserved (1024/1564 co-resident).
// ---------------------------------------------------------------------------
__global__ __launch_bounds__(256, 4) void pull_lds_kernel(
    const int* __restrict__ bseg, const int2* __restrict__ csr,
    const unsigned* __restrict__ in16w, float4* __restrict__ rep4,
    const float* __restrict__ mix) {
    __shared__ float acc[64 * 128];     // 32KB
    int b = blockIdx.x >> 1;
    int h = blockIdx.x & 1;
    int t = threadIdx.x;
    int rbase = (b << B_SHIFT) + (h << 6);
    float m0 = mix[0];

    // init: acc[r][:] = m0 * input16[rbase+r][:]
    for (int i = t; i < 64 * 64; i += 256) {
        int r = i >> 6, c = i & 63;
        int row = rbase + r;
        if (row < N_NODES) {
            unsigned u = in16w[(row << 6) | c];
            float2 f = __half22float2(*reinterpret_cast<const __half2*>(&u));
            acc[r * 128 + 2 * c]     = m0 * f.x;
            acc[r * 128 + 2 * c + 1] = m0 * f.y;
        }
    }
    __syncthreads();

    int w = t >> 6;          // wave 0..3
    int l = t & 63;
    const int* bs = bseg + b * (NBIN + 1);

    for (int s = 0; s < NSEG; ++s) {
        int i0 = bs[s * 2 + h];
        int i1 = bs[s * 2 + h + 1];
        int len = i1 - i0;
        int j  = i0 + ((len * w) >> 2);
        int je = i0 + ((len * (w + 1)) >> 2);
        for (; j + 4 <= je; j += 4) {
            int2 e0 = csr[j + 0];
            int2 e1 = csr[j + 1];
            int2 e2 = csr[j + 2];
            int2 e3 = csr[j + 3];
            unsigned y0 = in16w[(unsigned)((e0.x & 0x01FFFFFF) << 6) | l];
            unsigned y1 = in16w[(unsigned)((e1.x & 0x01FFFFFF) << 6) | l];
            unsigned y2 = in16w[(unsigned)((e2.x & 0x01FFFFFF) << 6) | l];
            unsigned y3 = in16w[(unsigned)((e3.x & 0x01FFFFFF) << 6) | l];
            {
                float v = __int_as_float(e0.y);
                float2 f = __half22float2(*reinterpret_cast<const __half2*>(&y0));
                int rl = (((unsigned)e0.x) >> 25) & 63;
                atomicAdd(&acc[rl * 128 + 2 * l],     v * f.x);
                atomicAdd(&acc[rl * 128 + 2 * l + 1], v * f.y);
            }
            {
                float v = __int_as_float(e1.y);
                float2 f = __half22float2(*reinterpret_cast<const __half2*>(&y1));
                int rl = (((unsigned)e1.x) >> 25) & 63;
                atomicAdd(&acc[rl * 128 + 2 * l],     v * f.x);
                atomicAdd(&acc[rl * 128 + 2 * l + 1], v * f.y);
            }
            {
                float v = __int_as_float(e2.y);
                float2 f = __half22float2(*reinterpret_cast<const __half2*>(&y2));
                int rl = (((unsigned)e2.x) >> 25) & 63;
                atomicAdd(&acc[rl * 128 + 2 * l],     v * f.x);
                atomicAdd(&acc[rl * 128 + 2 * l + 1], v * f.y);
            }
            {
                float v = __int_as_float(e3.y);
                float2 f = __half22float2(*reinterpret_cast<const __half2*>(&y3));
                int rl = (((unsigned)e3.x) >> 25) & 63;
                atomicAdd(&acc[rl * 128 + 2 * l],     v * f.x);
                atomicAdd(&acc[rl * 128 + 2 * l + 1], v * f.y);
            }
        }
        for (; j < je; ++j) {
            int2 e = csr[j];
            unsigned y = in16w[(unsigned)((e.x & 0x01FFFFFF) << 6) | l];
            float v = __int_as_float(e.y);
            float2 f = __half22float2(*reinterpret_cast<const __half2*>(&y));
            int rl = (((unsigned)e.x) >> 25) & 63;
            atomicAdd(&acc[rl * 128 + 2 * l],     v * f.x);
            atomicAdd(&acc[rl * 128 + 2 * l + 1], v * f.y);
        }
    }
    __syncthreads();

    // writeout: 64 rows x 32 float4
    for (int i = t; i < 64 * 32; i += 256) {
        int r = i >> 5, c = i & 31;
        int row = rbase + r;
        if (row < N_NODES) {
            const float* p = &acc[r * 128 + c * 4];
            rep4[(row << 5) | c] = make_float4(p[0], p[1], p[2], p[3]);
        }
    }
}

// ---------------------------------------------------------------------------
// Pull (fp16 transient, middle path): r4 version.
// ---------------------------------------------------------------------------
__device__ __forceinline__ void h8_fma(uint4 u, float v, float* a) {
    __half2* hp = reinterpret_cast<__half2*>(&u);
    #pragma unroll
    for (int k = 0; k < 4; ++k) {
        float2 f = __half22float2(hp[k]);
        a[2 * k]     += v * f.x;
        a[2 * k + 1] += v * f.y;
    }
}

__global__ __launch_bounds__(256) void pull16_kernel(
    const int* __restrict__ offsets, const int2* __restrict__ csr,
    const uint4* __restrict__ in16, float4* __restrict__ rep4,
    const float* __restrict__ mix) {
    int row = blockIdx.x * 16 + (threadIdx.x >> 4);
    int l = threadIdx.x & 15;
    if (row >= N_NODES) return;
    int j = offsets[row];
    int end = offsets[row + 1];
    float m0 = mix[0];
    float a[8];
    {
        uint4 xs = in16[(row << 4) | l];
        __half2* hp = reinterpret_cast<__half2*>(&xs);
        #pragma unroll
        for (int k = 0; k < 4; ++k) {
            float2 f = __half22float2(hp[k]);
            a[2 * k]     = m0 * f.x;
            a[2 * k + 1] = m0 * f.y;
        }
    }
    for (; j + 4 <= end; j += 4) {
        int2 e0 = csr[j + 0];
        int2 e1 = csr[j + 1];
        int2 e2 = csr[j + 2];
        int2 e3 = csr[j + 3];
        uint4 y0 = in16[(e0.x << 4) | l];
        uint4 y1 = in16[(e1.x << 4) | l];
        uint4 y2 = in16[(e2.x << 4) | l];
        uint4 y3 = in16[(e3.x << 4) | l];
        h8_fma(y0, __int_as_float(e0.y), a);
        h8_fma(y1, __int_as_float(e1.y), a);
        h8_fma(y2, __int_as_float(e2.y), a);
        h8_fma(y3, __int_as_float(e3.y), a);
    }
    for (; j < end; ++j) {
        int2 e = csr[j];
        uint4 y = in16[(e.x << 4) | l];
        h8_fma(y, __int_as_float(e.y), a);
    }
    int o = (row << 5) | (l << 1);
    rep4[o]     = make_float4(a[0], a[1], a[2], a[3]);
    rep4[o + 1] = make_float4(a[4], a[5], a[6], a[7]);
}

// ---------------------------------------------------------------------------
// Pull (f32, when ws can't hold input16)
// ---------------------------------------------------------------------------
__global__ __launch_bounds__(256) void pull_kernel(
    const int* __restrict__ offsets, const int2* __restrict__ csr,
    const float4* __restrict__ in4, float4* __restrict__ rep4,
    const float* __restrict__ mix) {
    int row = blockIdx.x * 8 + (threadIdx.x >> 5);
    int l = threadIdx.x & 31;
    if (row >= N_NODES) return;
    int j = offsets[row];
    int end = offsets[row + 1];
    float m0 = mix[0];
    float4 x = in4[(row << 5) | l];
    float4 acc = make_float4(m0 * x.x, m0 * x.y, m0 * x.z, m0 * x.w);
    for (; j + 1 < end; j += 2) {
        int2 e0 = csr[j];
        int2 e1 = csr[j + 1];
        float v0 = __int_as_float(e0.y);
        float v1 = __int_as_float(e1.y);
        float4 y0 = in4[(e0.x << 5) | l];
        float4 y1 = in4[(e1.x << 5) | l];
        acc.x += v0 * y0.x; acc.y += v0 * y0.y; acc.z += v0 * y0.z; acc.w += v0 * y0.w;
        acc.x += v1 * y1.x; acc.y += v1 * y1.y; acc.z += v1 * y1.z; acc.w += v1 * y1.w;
    }
    if (j < end) {
        int2 e0 = csr[j];
        float v0 = __int_as_float(e0.y);
        float4 y0 = in4[(e0.x << 5) | l];
        acc.x += v0 * y0.x; acc.y += v0 * y0.y; acc.z += v0 * y0.z; acc.w += v0 * y0.w;
    }
    rep4[(row << 5) | l] = acc;
}

// ---------------------------------------------------------------------------
// Fallback path (small ws): rep = mix[0]*input, then atomic push-scatter
// ---------------------------------------------------------------------------
__global__ __launch_bounds__(256) void rep_init_kernel(
    const float4* __restrict__ in4, float4* __restrict__ rep4,
    const float* __restrict__ mix) {
    int i = blockIdx.x * blockDim.x + threadIdx.x;
    if (i >= N_NODES * D / 4) return;
    float m0 = mix[0];
    float4 v = in4[i];
    v.x *= m0; v.y *= m0; v.z *= m0; v.w *= m0;
    rep4[i] = v;
}

__global__ __launch_bounds__(256) void scatter_kernel(
    const int* __restrict__ rows, const int* __restrict__ cols,
    const float* __restrict__ vals, const float4* __restrict__ in4,
    float* __restrict__ rep, const float* __restrict__ mix) {
    long long gid = (long long)blockIdx.x * blockDim.x + threadIdx.x;
    int e = (int)(gid >> 5);
    int l = (int)(gid & 31);
    if (e >= EDGES_TOTAL) return;
    int a = e / NNZ;
    int row = rows[e];
    int col = cols[e];
    float v = vals[e] * mix[a + 1];
    float4 x = in4[col * 32 + l];
    float* dst = rep + (long long)row * D + l * 4;
    atomicAdd(dst + 0, v * x.x);
    atomicAdd(dst + 1, v * x.y);
    atomicAdd(dst + 2, v * x.z);
    atomicAdd(dst + 3, v * x.w);
}

// ---------------------------------------------------------------------------
// out = rep @ W + bias. Register-blocked: 4 rows per thread (r4 win).
// ---------------------------------------------------------------------------
__global__ __launch_bounds__(256) void gemm_kernel(
    const float4* __restrict__ rep4, const float4* __restrict__ w4,
    const float4* __restrict__ bias4, float4* __restrict__ out4) {
    __shared__ float4 Wlds[D * (D / 4)];

    for (int idx = threadIdx.x; idx < D * (D / 4); idx += 256)
        Wlds[idx] = w4[idx];
    __syncthreads();

    int tc = threadIdx.x & 31;
    int rg = threadIdx.x >> 5;

    for (int base = blockIdx.x * 32; base < N_NODES; base += gridDim.x * 32) {
        int row0 = base + rg * 4;
        const float4* r0 = rep4 + (size_t)row0 * (D / 4);
        float4 acc0 = make_float4(0.f, 0.f, 0.f, 0.f);
        float4 acc1 = make_float4(0.f, 0.f, 0.f, 0.f);
        float4 acc2 = make_float4(0.f, 0.f, 0.f, 0.f);
        float4 acc3 = make_float4(0.f, 0.f, 0.f, 0.f);
        #pragma unroll 2
        for (int k4 = 0; k4 < D / 4; ++k4) {
            float4 a0 = r0[k4];
            float4 a1 = r0[(D / 4) + k4];
            float4 a2 = r0[2 * (D / 4) + k4];
            float4 a3 = r0[3 * (D / 4) + k4];
            float4 w0 = Wlds[(k4 * 4 + 0) * 32 + tc];
            float4 w1 = Wlds[(k4 * 4 + 1) * 32 + tc];
            float4 w2 = Wlds[(k4 * 4 + 2) * 32 + tc];
            float4 w3 = Wlds[(k4 * 4 + 3) * 32 + tc];
            acc0.x += a0.x * w0.x; acc0.y += a0.x * w0.y; acc0.z += a0.x * w0.z; acc0.w += a0.x * w0.w;
            acc0.x += a0.y * w1.x; acc0.y += a0.y * w1.y; acc0.z += a0.y * w1.z; acc0.w += a0.y * w1.w;
            acc0.x += a0.z * w2.x; acc0.y += a0.z * w2.y; acc0.z += a0.z * w2.z; acc0.w += a0.z * w2.w;
            acc0.x += a0.w * w3.x; acc0.y += a0.w * w3.y; acc0.z += a0.w * w3.z; acc0.w += a0.w * w3.w;
            acc1.x += a1.x * w0.x; acc1.y += a1.x * w0.y; acc1.z += a1.x * w0.z; acc1.w += a1.x * w0.w;
            acc1.x += a1.y * w1.x; acc1.y += a1.y * w1.y; acc1.z += a1.y * w1.z; acc1.w += a1.y * w1.w;
            acc1.x += a1.z * w2.x; acc1.y += a1.z * w2.y; acc1.z += a1.z * w2.z; acc1.w += a1.z * w2.w;
            acc1.x += a1.w * w3.x; acc1.y += a1.w * w3.y; acc1.z += a1.w * w3.z; acc1.w += a1.w * w3.w;
            acc2.x += a2.x * w0.x; acc2.y += a2.x * w0.y; acc2.z += a2.x * w0.z; acc2.w += a2.x * w0.w;
            acc2.x += a2.y * w1.x; acc2.y += a2.y * w1.y; acc2.z += a2.y * w1.z; acc2.w += a2.y * w1.w;
            acc2.x += a2.z * w2.x; acc2.y += a2.z * w2.y; acc2.z += a2.z * w2.z; acc2.w += a2.z * w2.w;
            acc2.x += a2.w * w3.x; acc2.y += a2.w * w3.y; acc2.z += a2.w * w3.z; acc2.w += a2.w * w3.w;
            acc3.x += a3.x * w0.x; acc3.y += a3.x * w0.y; acc3.z += a3.x * w0.z; acc3.w += a3.x * w0.w;
            acc3.x += a3.y * w1.x; acc3.y += a3.y * w1.y; acc3.z += a3.y * w1.z; acc3.w += a3.y * w1.w;
            acc3.x += a3.z * w2.x; acc3.y += a3.z * w2.y; acc3.z += a3.z * w2.z; acc3.w += a3.z * w2.w;
            acc3.x += a3.w * w3.x; acc3.y += a3.w * w3.y; acc3.z += a3.w * w3.z; acc3.w += a3.w * w3.w;
        }
        float4 b = bias4[tc];
        acc0.x += b.x; acc0.y += b.y; acc0.z += b.z; acc0.w += b.w;
        acc1.x += b.x; acc1.y += b.y; acc1.z += b.z; acc1.w += b.w;
        acc2.x += b.x; acc2.y += b.y; acc2.z += b.z; acc2.w += b.w;
        acc3.x += b.x; acc3.y += b.y; acc3.z += b.z; acc3.w += b.w;
        out4[(size_t)(row0 + 0) * (D / 4) + tc] = acc0;
        out4[(size_t)(row0 + 1) * (D / 4) + tc] = acc1;
        out4[(size_t)(row0 + 2) * (D / 4) + tc] = acc2;
        out4[(size_t)(row0 + 3) * (D / 4) + tc] = acc3;
    }
}

// ---------------------------------------------------------------------------
extern "C" void kernel_launch(void* const* d_in, const int* in_sizes, int n_in,
                              void* d_out, int out_size, void* d_ws, size_t ws_size,
                              hipStream_t stream) {
    const float* input         = (const float*)d_in[0];
    const int*   adj_rows      = (const int*)d_in[1];
    const int*   adj_cols      = (const int*)d_in[2];
    const float* adj_vals      = (const float*)d_in[3];
    const float* weight        = (const float*)d_in[4];
    const float* linear_weight = (const float*)d_in[5];
    const float* bias          = (const float*)d_in[6];

    float* out = (float*)d_out;                    // [N_NODES, D]
    float* rep = out + (size_t)N_NODES * D;        // [N_NODES, D]
    int2* tmp = (int2*)out;                        // 35.2MB <= 51.2MB alias

    // workspace layout
    char* ws = (char*)d_ws;
    float* mix      = (float*)ws;                        ws += 32;
    int*   counts   = (int*)ws;                          ws += sizeof(int) * N_NODES;
    int*   offsets  = (int*)ws;                          ws += sizeof(int) * (N_NODES + 4);
    int*   blockSums= (int*)ws;                          ws += sizeof(int) * 128;
    int*   bpos     = (int*)ws;                          ws += sizeof(int) * (NB + 2);
    int*   bbase    = (int*)ws;                          ws += sizeof(int) * (NB + 2);
    ws = (char*)(((uintptr_t)ws + 15) & ~(uintptr_t)15);
    int2*  csr      = (int2*)ws;                         ws += sizeof(int2) * EDGES_TOTAL;
    size_t needed1 = (size_t)(ws - (char*)d_ws);
    ws = (char*)(((uintptr_t)ws + 15) & ~(uintptr_t)15);
    uint4* input16  = (uint4*)ws;                        ws += sizeof(unsigned short) * (size_t)N_NODES * D;
    size_t needed2 = (size_t)(ws - (char*)d_ws);
    int*   bseg     = (int*)ws;                          ws += sizeof(int) * (size_t)NB * (NBIN + 1);
    size_t needed3 = (size_t)(ws - (char*)d_ws);

    softmax_mix_kernel<<<1, 64, 0, stream>>>(linear_weight, mix);

    if (ws_size >= needed1) {
        bool fp16path = (ws_size >= needed2);
        bool segpath  = (ws_size >= needed3);

        if (fp16path) {
            int total = N_NODES * D / 8;
            conv16_kernel<<<(total + 255) / 256, 256, 0, stream>>>(
                (const float4*)input, input16);
        }

        if (fp16path && segpath) {
            // ---- main path: fixed-cap buckets, (seg,h) bins, LDS-acc pull --
            bpos_init_cap_kernel<<<(NB + 255) / 256, 256, 0, stream>>>(bpos);
            {
                int blocks = (EDGES_TOTAL + CHUNK - 1) / CHUNK;
                bucket_scatter_kernel<<<blocks, 256, 0, stream>>>(
                    adj_rows, adj_cols, adj_vals, mix, bpos, tmp);
            }
            bbase_scan_kernel<<<1, 64, 0, stream>>>(bpos, bbase);
            bucket_to_csr_binh_kernel<<<NB, 256, 0, stream>>>(
                bpos, tmp, bbase, csr, bseg);
            pull_lds_kernel<<<PULL_BLOCKS, 256, 0, stream>>>(
                bseg, csr, (const unsigned*)input16, (float4*)rep, mix);
        } else {
            // ---- middle paths: original offsets-based pipeline ----
            hipMemsetAsync(counts, 0, sizeof(int) * N_NODES, stream);
            {
                int blocks = (EDGES_TOTAL + 255) / 256;
                hist_kernel<<<blocks, 256, 0, stream>>>(adj_rows, counts);
            }
            scan_partial_kernel<<<SCAN_BLOCKS, 256, 0, stream>>>(counts, blockSums);
            scan_blocksums_kernel<<<1, 64, 0, stream>>>(blockSums);
            scan_final_kernel<<<SCAN_BLOCKS, 256, 0, stream>>>(counts, blockSums, offsets);
            bpos_init_kernel<<<(NB + 255) / 256, 256, 0, stream>>>(offsets, bpos);
            {
                int blocks = (EDGES_TOTAL + CHUNK - 1) / CHUNK;
                bucket_scatter_kernel<<<blocks, 256, 0, stream>>>(
                    adj_rows, adj_cols, adj_vals, mix, bpos, tmp);
            }
            bucket_to_csr_kernel<<<NB, 256, 0, stream>>>(offsets, tmp, csr);
            if (fp16path) {
                int blocks = (N_NODES * 16 + 255) / 256;
                pull16_kernel<<<blocks, 256, 0, stream>>>(
                    offsets, csr, input16, (float4*)rep, mix);
            } else {
                long long threads = (long long)N_NODES * 32;
                int blocks = (int)((threads + 255) / 256);
                pull_kernel<<<blocks, 256, 0, stream>>>(
                    offsets, csr, (const float4*)input, (float4*)rep, mix);
            }
        }
    } else {
        {
            int total = N_NODES * D / 4;
            int blocks = (total + 255) / 256;
            rep_init_kernel<<<blocks, 256, 0, stream>>>(
                (const float4*)input, (float4*)rep, mix);
        }
        {
            long long threads = (long long)EDGES_TOTAL * 32;
            int blocks = (int)((threads + 255) / 256);
            scatter_kernel<<<blocks, 256, 0, stream>>>(
                adj_rows, adj_cols, adj_vals, (const float4*)input, rep, mix);
        }
    }

    gemm_kernel<<<2048, 256, 0, stream>>>(
        (const float4*)rep, (const float4*)weight,
        (const float4*)bias, (float4*)out);
}

// Round 10
// 608.437 us; speedup vs baseline: 4.9225x; 4.9225x over previous
//
#include <hip/hip_runtime.h>
#include <hip/hip_fp16.h>

#define N_NODES 100000
#define D 128
#define N_ADJ 6
#define NNZ 600000
#define N_HOPS 7
#define EDGES_TOTAL (N_ADJ * NNZ)

#define SCAN_CHUNK 1024
#define SCAN_BLOCKS ((N_NODES + SCAN_CHUNK - 1) / SCAN_CHUNK)  // 98

#define B_SHIFT 7
#define B_ROWS 128
#define NB ((N_NODES + B_ROWS - 1) / B_ROWS)   // 782 buckets
#define CHUNK 4096                              // edges per passA workgroup
#define EPT 16                                  // edges per thread (CHUNK/256)

// Fixed bucket capacity: counts ~ Poisson(4608), sigma=68. CAP = mean+15sigma.
#define BCAP 5632

// Column segments for gather locality: 8192 nodes x 256B fp16 = 2MB < 4MB/XCD L2
#define SEG_SHIFT 13
#define NSEG 13                                 // ceil(100000 / 8192)
#define SEGP1 14

// Pull: 3 rows per 16-lane group -> 533k threads ~ device thread capacity
// (524k): ~full occupancy AND ~98% block co-residency (lockstep preserved).
#define PULL_BLOCK_ROWS 48                      // 16 groups x 3 rows
#define PULL_BLOCKS ((N_NODES + PULL_BLOCK_ROWS - 1) / PULL_BLOCK_ROWS)  // 2084

// ---------------------------------------------------------------------------
// Phase 0: mix = softmax(linear_weight), 7 elements
// ---------------------------------------------------------------------------
__global__ void softmax_mix_kernel(const float* __restrict__ lw,
                                   float* __restrict__ mix) {
    if (threadIdx.x == 0) {
        float m = lw[0];
        for (int i = 1; i < N_HOPS; ++i) m = fmaxf(m, lw[i]);
        float e[N_HOPS];
        float s = 0.f;
        for (int i = 0; i < N_HOPS; ++i) { e[i] = __expf(lw[i] - m); s += e[i]; }
        float inv = 1.f / s;
        for (int i = 0; i < N_HOPS; ++i) mix[i] = e[i] * inv;
    }
}

// ---------------------------------------------------------------------------
// input (f32) -> input16 (fp16). 8 floats per thread, 16B stores.
// ---------------------------------------------------------------------------
__global__ __launch_bounds__(256) void conv16_kernel(
    const float4* __restrict__ in4, uint4* __restrict__ o16) {
    int i = blockIdx.x * 256 + threadIdx.x;
    if (i >= N_NODES * D / 8) return;
    float4 a = in4[2 * i];
    float4 b = in4[2 * i + 1];
    __half2 h0 = __floats2half2_rn(a.x, a.y);
    __half2 h1 = __floats2half2_rn(a.z, a.w);
    __half2 h2 = __floats2half2_rn(b.x, b.y);
    __half2 h3 = __floats2half2_rn(b.z, b.w);
    uint4 u;
    u.x = *reinterpret_cast<unsigned int*>(&h0);
    u.y = *reinterpret_cast<unsigned int*>(&h1);
    u.z = *reinterpret_cast<unsigned int*>(&h2);
    u.w = *reinterpret_cast<unsigned int*>(&h3);
    o16[i] = u;
}

// ---------------------------------------------------------------------------
// Middle/fallback path kernels (hist + scans + offsets pipeline)
// ---------------------------------------------------------------------------
__global__ __launch_bounds__(256) void hist_kernel(
    const int* __restrict__ rows, int* __restrict__ counts) {
    int e = blockIdx.x * 256 + threadIdx.x;
    if (e < EDGES_TOTAL) atomicAdd(&counts[rows[e]], 1);
}

__global__ __launch_bounds__(256) void scan_partial_kernel(
    const int* __restrict__ counts, int* __restrict__ blockSums) {
    __shared__ int lds[256];
    int base = blockIdx.x * SCAN_CHUNK;
    int t = threadIdx.x;
    int s = 0;
    #pragma unroll
    for (int k = 0; k < 4; ++k) {
        int i = base + t * 4 + k;
        s += (i < N_NODES) ? counts[i] : 0;
    }
    lds[t] = s;
    __syncthreads();
    for (int off = 128; off > 0; off >>= 1) {
        if (t < off) lds[t] += lds[t + off];
        __syncthreads();
    }
    if (t == 0) blockSums[blockIdx.x] = lds[0];
}

__global__ void scan_blocksums_kernel(int* __restrict__ blockSums) {
    if (threadIdx.x == 0) {
        int run = 0;
        for (int i = 0; i < SCAN_BLOCKS; ++i) {
            int c = blockSums[i];
            blockSums[i] = run;
            run += c;
        }
    }
}

__global__ __launch_bounds__(256) void scan_final_kernel(
    const int* __restrict__ counts, const int* __restrict__ blockSums,
    int* __restrict__ offsets) {
    __shared__ int lds[256];
    int base = blockIdx.x * SCAN_CHUNK;
    int t = threadIdx.x;
    int c[4];
    int s = 0;
    #pragma unroll
    for (int k = 0; k < 4; ++k) {
        int i = base + t * 4 + k;
        c[k] = (i < N_NODES) ? counts[i] : 0;
        s += c[k];
    }
    lds[t] = s;
    __syncthreads();
    for (int off = 1; off < 256; off <<= 1) {
        int u = 0;
        if (t >= off) u = lds[t - off];
        __syncthreads();
        if (t >= off) lds[t] += u;
        __syncthreads();
    }
    int texcl = lds[t] - s;
    int run = blockSums[blockIdx.x] + texcl;
    #pragma unroll
    for (int k = 0; k < 4; ++k) {
        int i = base + t * 4 + k;
        if (i < N_NODES) offsets[i] = run;
        run += c[k];
    }
    if (blockIdx.x == 0 && t == 0) offsets[N_NODES] = EDGES_TOTAL;
}

__global__ void bpos_init_kernel(const int* __restrict__ offsets,
                                 int* __restrict__ bpos) {
    int b = blockIdx.x * 256 + threadIdx.x;
    if (b < NB) bpos[b] = offsets[b << B_SHIFT];
}

__global__ void bpos_init_cap_kernel(int* __restrict__ bpos) {
    int b = blockIdx.x * 256 + threadIdx.x;
    if (b < NB) bpos[b] = b * BCAP;
}

// ---------------------------------------------------------------------------
// bbase scan: bucket counts from pass A cursors -> csr base per bucket.
// ---------------------------------------------------------------------------
__global__ void bbase_scan_kernel(const int* __restrict__ bpos,
                                  int* __restrict__ bbase) {
    if (threadIdx.x == 0) {
        int run = 0;
        for (int b = 0; b < NB; ++b) {
            bbase[b] = run;
            run += bpos[b] - b * BCAP;
        }
    }
}

// ---------------------------------------------------------------------------
// Pass A: LDS-aggregated bucket scatter (r0 flush; works with either bpos).
// ---------------------------------------------------------------------------
__global__ __launch_bounds__(256) void bucket_scatter_kernel(
    const int* __restrict__ rows, const int* __restrict__ cols,
    const float* __restrict__ vals, const float* __restrict__ mix,
    int* __restrict__ bpos, int2* __restrict__ tmp) {
    __shared__ int cnt[NB];
    __shared__ int off[NB];
    __shared__ int gbase[NB];
    __shared__ int scanbuf[256];
    __shared__ int2 stage[CHUNK];

    int base = blockIdx.x * CHUNK;
    int t = threadIdx.x;

    for (int i = t; i < NB; i += 256) cnt[i] = 0;
    __syncthreads();

    int myRow[EPT];
    int mySlot[EPT];
    #pragma unroll
    for (int k = 0; k < EPT; ++k) {
        int e = base + k * 256 + t;
        if (e < EDGES_TOTAL) {
            int r = rows[e];
            myRow[k] = r;
            mySlot[k] = atomicAdd(&cnt[r >> B_SHIFT], 1);
        } else {
            myRow[k] = -1;
            mySlot[k] = 0;
        }
    }
    __syncthreads();

    int i0 = t * 4;
    int c4[4];
    int s = 0;
    #pragma unroll
    for (int k = 0; k < 4; ++k) {
        int i = i0 + k;
        c4[k] = (i < NB) ? cnt[i] : 0;
        s += c4[k];
    }
    scanbuf[t] = s;
    __syncthreads();
    for (int o = 1; o < 256; o <<= 1) {
        int u = 0;
        if (t >= o) u = scanbuf[t - o];
        __syncthreads();
        if (t >= o) scanbuf[t] += u;
        __syncthreads();
    }
    int run = scanbuf[t] - s;
    #pragma unroll
    for (int k = 0; k < 4; ++k) {
        int i = i0 + k;
        if (i < NB) off[i] = run;
        run += c4[k];
    }
    for (int i = t; i < NB; i += 256)
        gbase[i] = atomicAdd(&bpos[i], cnt[i]);
    __syncthreads();

    #pragma unroll
    for (int k = 0; k < EPT; ++k) {
        int e = base + k * 256 + t;
        int r = myRow[k];
        if (r >= 0) {
            int b = r >> B_SHIFT;
            int rl = r & (B_ROWS - 1);
            int a = e / NNZ;
            float v = vals[e] * mix[a + 1];
            int packed = (rl << 25) | cols[e];
            stage[off[b] + mySlot[k]] = make_int2(packed, __float_as_int(v));
        }
    }
    __syncthreads();

    for (int i = t; i < NB; i += 256) {
        int c = cnt[i];
        int g = gbase[i];
        int o = off[i];
        for (int j = 0; j < c; ++j) tmp[g + j] = stage[o + j];
    }
}

// ---------------------------------------------------------------------------
// Pass B (main path, r8): self-contained per-(row,seg) reorder. Counts
// (row,seg) in LDS, 128-row scan, cursors from bbase, emits segoff, scatters
// into (row,seg)-ordered CSR. No `offsets` in the main path.
// ---------------------------------------------------------------------------
__global__ __launch_bounds__(256) void bucket_to_csr_seg2_kernel(
    const int* __restrict__ bpos, const int2* __restrict__ tmp,
    const int* __restrict__ bbase, int2* __restrict__ csr,
    int* __restrict__ segoff) {
    __shared__ int cur[B_ROWS * NSEG];
    __shared__ int rowsum[B_ROWS];
    __shared__ int rowscan[B_ROWS];
    int b = blockIdx.x;
    int t = threadIdx.x;
    int base = b * BCAP;
    int cnt = bpos[b] - base;
    int rbase = b << B_SHIFT;

    for (int i = t; i < B_ROWS * NSEG; i += 256) cur[i] = 0;
    __syncthreads();

    // pass 1: count (row, seg)
    for (int j = t; j < cnt; j += 256) {
        int2 eo = tmp[base + j];
        int rl = ((unsigned)eo.x) >> 25;
        int col = eo.x & 0x01FFFFFF;
        atomicAdd(&cur[rl * NSEG + (col >> SEG_SHIFT)], 1);
    }
    __syncthreads();

    // per-row totals
    if (t < B_ROWS) {
        int s = 0;
        #pragma unroll
        for (int q = 0; q < NSEG; ++q) s += cur[t * NSEG + q];
        rowsum[t] = s;
        rowscan[t] = s;
    }
    __syncthreads();
    // inclusive scan over 128 rows
    for (int o = 1; o < B_ROWS; o <<= 1) {
        int u = 0;
        if (t < B_ROWS && t >= o) u = rowscan[t - o];
        __syncthreads();
        if (t < B_ROWS && t >= o) rowscan[t] += u;
        __syncthreads();
    }

    // per-row cursors + segoff emission
    if (t < B_ROWS) {
        int r = rbase + t;
        if (r < N_NODES) {
            int c0 = bbase[b] + rowscan[t] - rowsum[t];   // exclusive start
            #pragma unroll
            for (int q = 0; q < NSEG; ++q) {
                int c = cur[t * NSEG + q];
                cur[t * NSEG + q] = c0;
                segoff[r * SEGP1 + q] = c0;
                c0 += c;
            }
            segoff[r * SEGP1 + NSEG] = c0;
        }
    }
    __syncthreads();

    // pass 2: scatter into (row, seg)-ordered CSR
    for (int j = t; j < cnt; j += 256) {
        int2 eo = tmp[base + j];
        int rl = ((unsigned)eo.x) >> 25;
        int col = eo.x & 0x01FFFFFF;
        int p = atomicAdd(&cur[rl * NSEG + (col >> SEG_SHIFT)], 1);
        csr[p] = make_int2(col, eo.y);
    }
}

// ---------------------------------------------------------------------------
// Pass B (plain, middle path): per-row cursors (r4 version).
// ---------------------------------------------------------------------------
__global__ __launch_bounds__(256) void bucket_to_csr_kernel(
    const int* __restrict__ offsets, const int2* __restrict__ tmp,
    int2* __restrict__ csr) {
    __shared__ int lpos[B_ROWS];
    int b = blockIdx.x;
    int rbase = b << B_SHIFT;
    int t = threadIdx.x;
    if (t < B_ROWS) {
        int r = rbase + t;
        lpos[t] = offsets[(r < N_NODES) ? r : N_NODES];
    }
    __syncthreads();
    int start = offsets[rbase];
    int endr = rbase + B_ROWS;
    int end = offsets[(endr < N_NODES) ? endr : N_NODES];
    for (int j = start + t; j < end; j += 256) {
        int2 eo = tmp[j];
        int rl = ((unsigned)eo.x) >> 25;
        int col = eo.x & 0x01FFFFFF;
        int p = atomicAdd(&lpos[rl], 1);
        csr[p] = make_int2(col, eo.y);
    }
}

// ---------------------------------------------------------------------------
// Pull v8 (persistent segment sweep, 3 rows/group): r9's edge-parallel LDS
// design catastrophically stalled (2629us, VALU 2.5%) -> reverted to the r8
// register-acc row-parallel structure. Change vs r8: 4 -> 3 rows per 16-lane
// group. 33334 groups x 16 = 533k threads ~ device capacity (524k) -> ~full
// occupancy (was 60%) while keeping ~98% of the 2084 blocks co-resident
// (lockstep sweep intact). VGPR ~48 (<=64 -> 8 waves/SIMD).
// ---------------------------------------------------------------------------
__device__ __forceinline__ void h8_fma(uint4 u, float v, float* a) {
    __half2* hp = reinterpret_cast<__half2*>(&u);
    #pragma unroll
    for (int k = 0; k < 4; ++k) {
        float2 f = __half22float2(hp[k]);
        a[2 * k]     += v * f.x;
        a[2 * k + 1] += v * f.y;
    }
}

__global__ __launch_bounds__(256, 8) void pull_seg_kernel(
    const int* __restrict__ segoff, const int2* __restrict__ csr,
    const uint4* __restrict__ in16, float4* __restrict__ rep4,
    const float* __restrict__ mix) {
    int g = threadIdx.x >> 4;            // 0..15
    int l = threadIdx.x & 15;
    int r0 = blockIdx.x * PULL_BLOCK_ROWS + g * 3;
    float m0 = mix[0];
    float a[3][8];

    #pragma unroll
    for (int k = 0; k < 3; ++k) {
        int r = r0 + k;
        if (r < N_NODES) {
            uint4 xs = in16[(r << 4) | l];
            __half2* hp = reinterpret_cast<__half2*>(&xs);
            #pragma unroll
            for (int q = 0; q < 4; ++q) {
                float2 f = __half22float2(hp[q]);
                a[k][2 * q]     = m0 * f.x;
                a[k][2 * q + 1] = m0 * f.y;
            }
        }
    }

    int s0[3];
    #pragma unroll
    for (int k = 0; k < 3; ++k) {
        int r = r0 + k;
        s0[k] = (r < N_NODES) ? segoff[r * SEGP1] : 0;
    }

    for (int seg = 0; seg < NSEG; ++seg) {
        #pragma unroll
        for (int k = 0; k < 3; ++k) {
            int r = r0 + k;
            if (r >= N_NODES) continue;
            int s1 = segoff[r * SEGP1 + seg + 1];
            int j = s0[k];
            for (; j + 2 <= s1; j += 2) {
                int2 e0 = csr[j];
                int2 e1 = csr[j + 1];
                uint4 y0 = in16[(e0.x << 4) | l];
                uint4 y1 = in16[(e1.x << 4) | l];
                h8_fma(y0, __int_as_float(e0.y), a[k]);
                h8_fma(y1, __int_as_float(e1.y), a[k]);
            }
            if (j < s1) {
                int2 e = csr[j];
                uint4 y = in16[(e.x << 4) | l];
                h8_fma(y, __int_as_float(e.y), a[k]);
            }
            s0[k] = s1;
        }
    }

    #pragma unroll
    for (int k = 0; k < 3; ++k) {
        int r = r0 + k;
        if (r < N_NODES) {
            int o = (r << 5) | (l << 1);
            rep4[o]     = make_float4(a[k][0], a[k][1], a[k][2], a[k][3]);
            rep4[o + 1] = make_float4(a[k][4], a[k][5], a[k][6], a[k][7]);
        }
    }
}

// ---------------------------------------------------------------------------
// Pull (fp16 transient, middle path): r4 version.
// ---------------------------------------------------------------------------
__global__ __launch_bounds__(256) void pull16_kernel(
    const int* __restrict__ offsets, const int2* __restrict__ csr,
    const uint4* __restrict__ in16, float4* __restrict__ rep4,
    const float* __restrict__ mix) {
    int row = blockIdx.x * 16 + (threadIdx.x >> 4);
    int l = threadIdx.x & 15;
    if (row >= N_NODES) return;
    int j = offsets[row];
    int end = offsets[row + 1];
    float m0 = mix[0];
    float a[8];
    {
        uint4 xs = in16[(row << 4) | l];
        __half2* hp = reinterpret_cast<__half2*>(&xs);
        #pragma unroll
        for (int k = 0; k < 4; ++k) {
            float2 f = __half22float2(hp[k]);
            a[2 * k]     = m0 * f.x;
            a[2 * k + 1] = m0 * f.y;
        }
    }
    for (; j + 4 <= end; j += 4) {
        int2 e0 = csr[j + 0];
        int2 e1 = csr[j + 1];
        int2 e2 = csr[j + 2];
        int2 e3 = csr[j + 3];
        uint4 y0 = in16[(e0.x << 4) | l];
        uint4 y1 = in16[(e1.x << 4) | l];
        uint4 y2 = in16[(e2.x << 4) | l];
        uint4 y3 = in16[(e3.x << 4) | l];
        h8_fma(y0, __int_as_float(e0.y), a);
        h8_fma(y1, __int_as_float(e1.y), a);
        h8_fma(y2, __int_as_float(e2.y), a);
        h8_fma(y3, __int_as_float(e3.y), a);
    }
    for (; j < end; ++j) {
        int2 e = csr[j];
        uint4 y = in16[(e.x << 4) | l];
        h8_fma(y, __int_as_float(e.y), a);
    }
    int o = (row << 5) | (l << 1);
    rep4[o]     = make_float4(a[0], a[1], a[2], a[3]);
    rep4[o + 1] = make_float4(a[4], a[5], a[6], a[7]);
}

// ---------------------------------------------------------------------------
// Pull (f32, when ws can't hold input16)
// ---------------------------------------------------------------------------
__global__ __launch_bounds__(256) void pull_kernel(
    const int* __restrict__ offsets, const int2* __restrict__ csr,
    const float4* __restrict__ in4, float4* __restrict__ rep4,
    const float* __restrict__ mix) {
    int row = blockIdx.x * 8 + (threadIdx.x >> 5);
    int l = threadIdx.x & 31;
    if (row >= N_NODES) return;
    int j = offsets[row];
    int end = offsets[row + 1];
    float m0 = mix[0];
    float4 x = in4[(row << 5) | l];
    float4 acc = make_float4(m0 * x.x, m0 * x.y, m0 * x.z, m0 * x.w);
    for (; j + 1 < end; j += 2) {
        int2 e0 = csr[j];
        int2 e1 = csr[j + 1];
        float v0 = __int_as_float(e0.y);
        float v1 = __int_as_float(e1.y);
        float4 y0 = in4[(e0.x << 5) | l];
        float4 y1 = in4[(e1.x << 5) | l];
        acc.x += v0 * y0.x; acc.y += v0 * y0.y; acc.z += v0 * y0.z; acc.w += v0 * y0.w;
        acc.x += v1 * y1.x; acc.y += v1 * y1.y; acc.z += v1 * y1.z; acc.w += v1 * y1.w;
    }
    if (j < end) {
        int2 e0 = csr[j];
        float v0 = __int_as_float(e0.y);
        float4 y0 = in4[(e0.x << 5) | l];
        acc.x += v0 * y0.x; acc.y += v0 * y0.y; acc.z += v0 * y0.z; acc.w += v0 * y0.w;
    }
    rep4[(row << 5) | l] = acc;
}

// ---------------------------------------------------------------------------
// Fallback path (small ws): rep = mix[0]*input, then atomic push-scatter
// ---------------------------------------------------------------------------
__global__ __launch_bounds__(256) void rep_init_kernel(
    const float4* __restrict__ in4, float4* __restrict__ rep4,
    const float* __restrict__ mix) {
    int i = blockIdx.x * blockDim.x + threadIdx.x;
    if (i >= N_NODES * D / 4) return;
    float m0 = mix[0];
    float4 v = in4[i];
    v.x *= m0; v.y *= m0; v.z *= m0; v.w *= m0;
    rep4[i] = v;
}

__global__ __launch_bounds__(256) void scatter_kernel(
    const int* __restrict__ rows, const int* __restrict__ cols,
    const float* __restrict__ vals, const float4* __restrict__ in4,
    float* __restrict__ rep, const float* __restrict__ mix) {
    long long gid = (long long)blockIdx.x * blockDim.x + threadIdx.x;
    int e = (int)(gid >> 5);
    int l = (int)(gid & 31);
    if (e >= EDGES_TOTAL) return;
    int a = e / NNZ;
    int row = rows[e];
    int col = cols[e];
    float v = vals[e] * mix[a + 1];
    float4 x = in4[col * 32 + l];
    float* dst = rep + (long long)row * D + l * 4;
    atomicAdd(dst + 0, v * x.x);
    atomicAdd(dst + 1, v * x.y);
    atomicAdd(dst + 2, v * x.z);
    atomicAdd(dst + 3, v * x.w);
}

// ---------------------------------------------------------------------------
// out = rep @ W + bias. Register-blocked: 4 rows per thread (r4 win).
// ---------------------------------------------------------------------------
__global__ __launch_bounds__(256) void gemm_kernel(
    const float4* __restrict__ rep4, const float4* __restrict__ w4,
    const float4* __restrict__ bias4, float4* __restrict__ out4) {
    __shared__ float4 Wlds[D * (D / 4)];

    for (int idx = threadIdx.x; idx < D * (D / 4); idx += 256)
        Wlds[idx] = w4[idx];
    __syncthreads();

    int tc = threadIdx.x & 31;
    int rg = threadIdx.x >> 5;

    for (int base = blockIdx.x * 32; base < N_NODES; base += gridDim.x * 32) {
        int row0 = base + rg * 4;
        const float4* r0 = rep4 + (size_t)row0 * (D / 4);
        float4 acc0 = make_float4(0.f, 0.f, 0.f, 0.f);
        float4 acc1 = make_float4(0.f, 0.f, 0.f, 0.f);
        float4 acc2 = make_float4(0.f, 0.f, 0.f, 0.f);
        float4 acc3 = make_float4(0.f, 0.f, 0.f, 0.f);
        #pragma unroll 2
        for (int k4 = 0; k4 < D / 4; ++k4) {
            float4 a0 = r0[k4];
            float4 a1 = r0[(D / 4) + k4];
            float4 a2 = r0[2 * (D / 4) + k4];
            float4 a3 = r0[3 * (D / 4) + k4];
            float4 w0 = Wlds[(k4 * 4 + 0) * 32 + tc];
            float4 w1 = Wlds[(k4 * 4 + 1) * 32 + tc];
            float4 w2 = Wlds[(k4 * 4 + 2) * 32 + tc];
            float4 w3 = Wlds[(k4 * 4 + 3) * 32 + tc];
            acc0.x += a0.x * w0.x; acc0.y += a0.x * w0.y; acc0.z += a0.x * w0.z; acc0.w += a0.x * w0.w;
            acc0.x += a0.y * w1.x; acc0.y += a0.y * w1.y; acc0.z += a0.y * w1.z; acc0.w += a0.y * w1.w;
            acc0.x += a0.z * w2.x; acc0.y += a0.z * w2.y; acc0.z += a0.z * w2.z; acc0.w += a0.z * w2.w;
            acc0.x += a0.w * w3.x; acc0.y += a0.w * w3.y; acc0.z += a0.w * w3.z; acc0.w += a0.w * w3.w;
            acc1.x += a1.x * w0.x; acc1.y += a1.x * w0.y; acc1.z += a1.x * w0.z; acc1.w += a1.x * w0.w;
            acc1.x += a1.y * w1.x; acc1.y += a1.y * w1.y; acc1.z += a1.y * w1.z; acc1.w += a1.y * w1.w;
            acc1.x += a1.z * w2.x; acc1.y += a1.z * w2.y; acc1.z += a1.z * w2.z; acc1.w += a1.z * w2.w;
            acc1.x += a1.w * w3.x; acc1.y += a1.w * w3.y; acc1.z += a1.w * w3.z; acc1.w += a1.w * w3.w;
            acc2.x += a2.x * w0.x; acc2.y += a2.x * w0.y; acc2.z += a2.x * w0.z; acc2.w += a2.x * w0.w;
            acc2.x += a2.y * w1.x; acc2.y += a2.y * w1.y; acc2.z += a2.y * w1.z; acc2.w += a2.y * w1.w;
            acc2.x += a2.z * w2.x; acc2.y += a2.z * w2.y; acc2.z += a2.z * w2.z; acc2.w += a2.z * w2.w;
            acc2.x += a2.w * w3.x; acc2.y += a2.w * w3.y; acc2.z += a2.w * w3.z; acc2.w += a2.w * w3.w;
            acc3.x += a3.x * w0.x; acc3.y += a3.x * w0.y; acc3.z += a3.x * w0.z; acc3.w += a3.x * w0.w;
            acc3.x += a3.y * w1.x; acc3.y += a3.y * w1.y; acc3.z += a3.y * w1.z; acc3.w += a3.y * w1.w;
            acc3.x += a3.z * w2.x; acc3.y += a3.z * w2.y; acc3.z += a3.z * w2.z; acc3.w += a3.z * w2.w;
            acc3.x += a3.w * w3.x; acc3.y += a3.w * w3.y; acc3.z += a3.w * w3.z; acc3.w += a3.w * w3.w;
        }
        float4 b = bias4[tc];
        acc0.x += b.x; acc0.y += b.y; acc0.z += b.z; acc0.w += b.w;
        acc1.x += b.x; acc1.y += b.y; acc1.z += b.z; acc1.w += b.w;
        acc2.x += b.x; acc2.y += b.y; acc2.z += b.z; acc2.w += b.w;
        acc3.x += b.x; acc3.y += b.y; acc3.z += b.z; acc3.w += b.w;
        out4[(size_t)(row0 + 0) * (D / 4) + tc] = acc0;
        out4[(size_t)(row0 + 1) * (D / 4) + tc] = acc1;
        out4[(size_t)(row0 + 2) * (D / 4) + tc] = acc2;
        out4[(size_t)(row0 + 3) * (D / 4) + tc] = acc3;
    }
}

// ---------------------------------------------------------------------------
extern "C" void kernel_launch(void* const* d_in, const int* in_sizes, int n_in,
                              void* d_out, int out_size, void* d_ws, size_t ws_size,
                              hipStream_t stream) {
    const float* input         = (const float*)d_in[0];
    const int*   adj_rows      = (const int*)d_in[1];
    const int*   adj_cols      = (const int*)d_in[2];
    const float* adj_vals      = (const float*)d_in[3];
    const float* weight        = (const float*)d_in[4];
    const float* linear_weight = (const float*)d_in[5];
    const float* bias          = (const float*)d_in[6];

    float* out = (float*)d_out;                    // [N_NODES, D]
    float* rep = out + (size_t)N_NODES * D;        // [N_NODES, D]
    int2* tmp = (int2*)out;                        // 35.2MB <= 51.2MB alias

    // workspace layout
    char* ws = (char*)d_ws;
    float* mix      = (float*)ws;                        ws += 32;
    int*   counts   = (int*)ws;                          ws += sizeof(int) * N_NODES;
    int*   offsets  = (int*)ws;                          ws += sizeof(int) * (N_NODES + 4);
    int*   blockSums= (int*)ws;                          ws += sizeof(int) * 128;
    int*   bpos     = (int*)ws;                          ws += sizeof(int) * (NB + 2);
    int*   bbase    = (int*)ws;                          ws += sizeof(int) * (NB + 2);
    ws = (char*)(((uintptr_t)ws + 15) & ~(uintptr_t)15);
    int2*  csr      = (int2*)ws;                         ws += sizeof(int2) * EDGES_TOTAL;
    size_t needed1 = (size_t)(ws - (char*)d_ws);
    ws = (char*)(((uintptr_t)ws + 15) & ~(uintptr_t)15);
    uint4* input16  = (uint4*)ws;                        ws += sizeof(unsigned short) * (size_t)N_NODES * D;
    size_t needed2 = (size_t)(ws - (char*)d_ws);
    int*   segoff   = (int*)ws;                          ws += sizeof(int) * (size_t)N_NODES * SEGP1;
    size_t needed3 = (size_t)(ws - (char*)d_ws);

    softmax_mix_kernel<<<1, 64, 0, stream>>>(linear_weight, mix);

    if (ws_size >= needed1) {
        bool fp16path = (ws_size >= needed2);
        bool segpath  = (ws_size >= needed3);

        if (fp16path) {
            int total = N_NODES * D / 8;
            conv16_kernel<<<(total + 255) / 256, 256, 0, stream>>>(
                (const float4*)input, input16);
        }

        if (fp16path && segpath) {
            // ---- main path: fixed-cap buckets, seg-ordered CSR, seg pull --
            bpos_init_cap_kernel<<<(NB + 255) / 256, 256, 0, stream>>>(bpos);
            {
                int blocks = (EDGES_TOTAL + CHUNK - 1) / CHUNK;
                bucket_scatter_kernel<<<blocks, 256, 0, stream>>>(
                    adj_rows, adj_cols, adj_vals, mix, bpos, tmp);
            }
            bbase_scan_kernel<<<1, 64, 0, stream>>>(bpos, bbase);
            bucket_to_csr_seg2_kernel<<<NB, 256, 0, stream>>>(
                bpos, tmp, bbase, csr, segoff);
            pull_seg_kernel<<<PULL_BLOCKS, 256, 0, stream>>>(
                segoff, csr, input16, (float4*)rep, mix);
        } else {
            // ---- middle paths: original offsets-based pipeline ----
            hipMemsetAsync(counts, 0, sizeof(int) * N_NODES, stream);
            {
                int blocks = (EDGES_TOTAL + 255) / 256;
                hist_kernel<<<blocks, 256, 0, stream>>>(adj_rows, counts);
            }
            scan_partial_kernel<<<SCAN_BLOCKS, 256, 0, stream>>>(counts, blockSums);
            scan_blocksums_kernel<<<1, 64, 0, stream>>>(blockSums);
            scan_final_kernel<<<SCAN_BLOCKS, 256, 0, stream>>>(counts, blockSums, offsets);
            bpos_init_kernel<<<(NB + 255) / 256, 256, 0, stream>>>(offsets, bpos);
            {
                int blocks = (EDGES_TOTAL + CHUNK - 1) / CHUNK;
                bucket_scatter_kernel<<<blocks, 256, 0, stream>>>(
                    adj_rows, adj_cols, adj_vals, mix, bpos, tmp);
            }
            bucket_to_csr_kernel<<<NB, 256, 0, stream>>>(offsets, tmp, csr);
            if (fp16path) {
                int blocks = (N_NODES * 16 + 255) / 256;
                pull16_kernel<<<blocks, 256, 0, stream>>>(
                    offsets, csr, input16, (float4*)rep, mix);
            } else {
                long long threads = (long long)N_NODES * 32;
                int blocks = (int)((threads + 255) / 256);
                pull_kernel<<<blocks, 256, 0, stream>>>(
                    offsets, csr, (const float4*)input, (float4*)rep, mix);
            }
        }
    } else {
        {
            int total = N_NODES * D / 4;
            int blocks = (total + 255) / 256;
            rep_init_kernel<<<blocks, 256, 0, stream>>>(
                (const float4*)input, (float4*)rep, mix);
        }
        {
            long long threads = (long long)EDGES_TOTAL * 32;
            int blocks = (int)((threads + 255) / 256);
            scatter_kernel<<<blocks, 256, 0, stream>>>(
                adj_rows, adj_cols, adj_vals, (const float4*)input, rep, mix);
        }
    }

    gemm_kernel<<<2048, 256, 0, stream>>>(
        (const float4*)rep, (const float4*)weight,
        (const float4*)bias, (float4*)out);
}

// Round 11
// 537.432 us; speedup vs baseline: 5.5729x; 1.1321x over previous
//
#include <hip/hip_runtime.h>
#include <hip/hip_fp16.h>

#define N_NODES 100000
#define D 128
#define N_ADJ 6
#define NNZ 600000
#define N_HOPS 7
#define EDGES_TOTAL (N_ADJ * NNZ)

#define SCAN_CHUNK 1024
#define SCAN_BLOCKS ((N_NODES + SCAN_CHUNK - 1) / SCAN_CHUNK)  // 98

#define B_SHIFT 7
#define B_ROWS 128
#define NB ((N_NODES + B_ROWS - 1) / B_ROWS)   // 782 buckets
#define CHUNK 4096                              // edges per passA workgroup
#define EPT 16                                  // edges per thread (CHUNK/256)

// Fixed bucket capacity: counts ~ Poisson(4608), sigma=68. CAP = mean+15sigma.
#define BCAP 5632

// Column segments for gather locality: 8192 nodes x 256B fp16 = 2MB < 4MB/XCD L2
#define SEG_SHIFT 13
#define NSEG 13                                 // ceil(100000 / 8192)
#define SEGP1 14

#define PULL_BLOCKS (NB * 2)                    // 1564 blocks, 64 rows each (r8)

// ---------------------------------------------------------------------------
// Phase 0: mix = softmax(linear_weight), 7 elements
// ---------------------------------------------------------------------------
__global__ void softmax_mix_kernel(const float* __restrict__ lw,
                                   float* __restrict__ mix) {
    if (threadIdx.x == 0) {
        float m = lw[0];
        for (int i = 1; i < N_HOPS; ++i) m = fmaxf(m, lw[i]);
        float e[N_HOPS];
        float s = 0.f;
        for (int i = 0; i < N_HOPS; ++i) { e[i] = __expf(lw[i] - m); s += e[i]; }
        float inv = 1.f / s;
        for (int i = 0; i < N_HOPS; ++i) mix[i] = e[i] * inv;
    }
}

// ---------------------------------------------------------------------------
// input (f32) -> input16 (fp16). 8 floats per thread, 16B stores.
// ---------------------------------------------------------------------------
__global__ __launch_bounds__(256) void conv16_kernel(
    const float4* __restrict__ in4, uint4* __restrict__ o16) {
    int i = blockIdx.x * 256 + threadIdx.x;
    if (i >= N_NODES * D / 8) return;
    float4 a = in4[2 * i];
    float4 b = in4[2 * i + 1];
    __half2 h0 = __floats2half2_rn(a.x, a.y);
    __half2 h1 = __floats2half2_rn(a.z, a.w);
    __half2 h2 = __floats2half2_rn(b.x, b.y);
    __half2 h3 = __floats2half2_rn(b.z, b.w);
    uint4 u;
    u.x = *reinterpret_cast<unsigned int*>(&h0);
    u.y = *reinterpret_cast<unsigned int*>(&h1);
    u.z = *reinterpret_cast<unsigned int*>(&h2);
    u.w = *reinterpret_cast<unsigned int*>(&h3);
    o16[i] = u;
}

// ---------------------------------------------------------------------------
// Middle/fallback path kernels (hist + scans + offsets pipeline)
// ---------------------------------------------------------------------------
__global__ __launch_bounds__(256) void hist_kernel(
    const int* __restrict__ rows, int* __restrict__ counts) {
    int e = blockIdx.x * 256 + threadIdx.x;
    if (e < EDGES_TOTAL) atomicAdd(&counts[rows[e]], 1);
}

__global__ __launch_bounds__(256) void scan_partial_kernel(
    const int* __restrict__ counts, int* __restrict__ blockSums) {
    __shared__ int lds[256];
    int base = blockIdx.x * SCAN_CHUNK;
    int t = threadIdx.x;
    int s = 0;
    #pragma unroll
    for (int k = 0; k < 4; ++k) {
        int i = base + t * 4 + k;
        s += (i < N_NODES) ? counts[i] : 0;
    }
    lds[t] = s;
    __syncthreads();
    for (int off = 128; off > 0; off >>= 1) {
        if (t < off) lds[t] += lds[t + off];
        __syncthreads();
    }
    if (t == 0) blockSums[blockIdx.x] = lds[0];
}

__global__ void scan_blocksums_kernel(int* __restrict__ blockSums) {
    if (threadIdx.x == 0) {
        int run = 0;
        for (int i = 0; i < SCAN_BLOCKS; ++i) {
            int c = blockSums[i];
            blockSums[i] = run;
            run += c;
        }
    }
}

__global__ __launch_bounds__(256) void scan_final_kernel(
    const int* __restrict__ counts, const int* __restrict__ blockSums,
    int* __restrict__ offsets) {
    __shared__ int lds[256];
    int base = blockIdx.x * SCAN_CHUNK;
    int t = threadIdx.x;
    int c[4];
    int s = 0;
    #pragma unroll
    for (int k = 0; k < 4; ++k) {
        int i = base + t * 4 + k;
        c[k] = (i < N_NODES) ? counts[i] : 0;
        s += c[k];
    }
    lds[t] = s;
    __syncthreads();
    for (int off = 1; off < 256; off <<= 1) {
        int u = 0;
        if (t >= off) u = lds[t - off];
        __syncthreads();
        if (t >= off) lds[t] += u;
        __syncthreads();
    }
    int texcl = lds[t] - s;
    int run = blockSums[blockIdx.x] + texcl;
    #pragma unroll
    for (int k = 0; k < 4; ++k) {
        int i = base + t * 4 + k;
        if (i < N_NODES) offsets[i] = run;
        run += c[k];
    }
    if (blockIdx.x == 0 && t == 0) offsets[N_NODES] = EDGES_TOTAL;
}

__global__ void bpos_init_kernel(const int* __restrict__ offsets,
                                 int* __restrict__ bpos) {
    int b = blockIdx.x * 256 + threadIdx.x;
    if (b < NB) bpos[b] = offsets[b << B_SHIFT];
}

__global__ void bpos_init_cap_kernel(int* __restrict__ bpos) {
    int b = blockIdx.x * 256 + threadIdx.x;
    if (b < NB) bpos[b] = b * BCAP;
}

// ---------------------------------------------------------------------------
// bbase scan v2: PARALLEL one-block scan over 782 bucket counts.
// r8-r10 used a single-thread loop: 782 DEPENDENT global load+store
// iterations ~ 65-100us of pure serial latency hidden between passA and
// passB. Now: 256 threads x 4 buckets, LDS Hillis-Steele -> ~4us.
// ---------------------------------------------------------------------------
__global__ __launch_bounds__(256) void bbase_scan_kernel(
    const int* __restrict__ bpos, int* __restrict__ bbase) {
    __shared__ int lds[256];
    int t = threadIdx.x;
    int c[4];
    int s = 0;
    #pragma unroll
    for (int k = 0; k < 4; ++k) {
        int b = t * 4 + k;
        c[k] = (b < NB) ? (bpos[b] - b * BCAP) : 0;
        s += c[k];
    }
    lds[t] = s;
    __syncthreads();
    for (int o = 1; o < 256; o <<= 1) {
        int u = 0;
        if (t >= o) u = lds[t - o];
        __syncthreads();
        if (t >= o) lds[t] += u;
        __syncthreads();
    }
    int run = lds[t] - s;
    #pragma unroll
    for (int k = 0; k < 4; ++k) {
        int b = t * 4 + k;
        if (b < NB) bbase[b] = run;
        run += c[k];
    }
}

// ---------------------------------------------------------------------------
// Pass A: LDS-aggregated bucket scatter (r0 flush; works with either bpos).
// ---------------------------------------------------------------------------
__global__ __launch_bounds__(256) void bucket_scatter_kernel(
    const int* __restrict__ rows, const int* __restrict__ cols,
    const float* __restrict__ vals, const float* __restrict__ mix,
    int* __restrict__ bpos, int2* __restrict__ tmp) {
    __shared__ int cnt[NB];
    __shared__ int off[NB];
    __shared__ int gbase[NB];
    __shared__ int scanbuf[256];
    __shared__ int2 stage[CHUNK];

    int base = blockIdx.x * CHUNK;
    int t = threadIdx.x;

    for (int i = t; i < NB; i += 256) cnt[i] = 0;
    __syncthreads();

    int myRow[EPT];
    int mySlot[EPT];
    #pragma unroll
    for (int k = 0; k < EPT; ++k) {
        int e = base + k * 256 + t;
        if (e < EDGES_TOTAL) {
            int r = rows[e];
            myRow[k] = r;
            mySlot[k] = atomicAdd(&cnt[r >> B_SHIFT], 1);
        } else {
            myRow[k] = -1;
            mySlot[k] = 0;
        }
    }
    __syncthreads();

    int i0 = t * 4;
    int c4[4];
    int s = 0;
    #pragma unroll
    for (int k = 0; k < 4; ++k) {
        int i = i0 + k;
        c4[k] = (i < NB) ? cnt[i] : 0;
        s += c4[k];
    }
    scanbuf[t] = s;
    __syncthreads();
    for (int o = 1; o < 256; o <<= 1) {
        int u = 0;
        if (t >= o) u = scanbuf[t - o];
        __syncthreads();
        if (t >= o) scanbuf[t] += u;
        __syncthreads();
    }
    int run = scanbuf[t] - s;
    #pragma unroll
    for (int k = 0; k < 4; ++k) {
        int i = i0 + k;
        if (i < NB) off[i] = run;
        run += c4[k];
    }
    for (int i = t; i < NB; i += 256)
        gbase[i] = atomicAdd(&bpos[i], cnt[i]);
    __syncthreads();

    #pragma unroll
    for (int k = 0; k < EPT; ++k) {
        int e = base + k * 256 + t;
        int r = myRow[k];
        if (r >= 0) {
            int b = r >> B_SHIFT;
            int rl = r & (B_ROWS - 1);
            int a = e / NNZ;
            float v = vals[e] * mix[a + 1];
            int packed = (rl << 25) | cols[e];
            stage[off[b] + mySlot[k]] = make_int2(packed, __float_as_int(v));
        }
    }
    __syncthreads();

    for (int i = t; i < NB; i += 256) {
        int c = cnt[i];
        int g = gbase[i];
        int o = off[i];
        for (int j = 0; j < c; ++j) tmp[g + j] = stage[o + j];
    }
}

// ---------------------------------------------------------------------------
// Pass B (main path, r8): self-contained per-(row,seg) reorder. Counts
// (row,seg) in LDS, 128-row scan, cursors from bbase, emits segoff, scatters
// into (row,seg)-ordered CSR.
// ---------------------------------------------------------------------------
__global__ __launch_bounds__(256) void bucket_to_csr_seg2_kernel(
    const int* __restrict__ bpos, const int2* __restrict__ tmp,
    const int* __restrict__ bbase, int2* __restrict__ csr,
    int* __restrict__ segoff) {
    __shared__ int cur[B_ROWS * NSEG];
    __shared__ int rowsum[B_ROWS];
    __shared__ int rowscan[B_ROWS];
    int b = blockIdx.x;
    int t = threadIdx.x;
    int base = b * BCAP;
    int cnt = bpos[b] - base;
    int rbase = b << B_SHIFT;

    for (int i = t; i < B_ROWS * NSEG; i += 256) cur[i] = 0;
    __syncthreads();

    // pass 1: count (row, seg)
    for (int j = t; j < cnt; j += 256) {
        int2 eo = tmp[base + j];
        int rl = ((unsigned)eo.x) >> 25;
        int col = eo.x & 0x01FFFFFF;
        atomicAdd(&cur[rl * NSEG + (col >> SEG_SHIFT)], 1);
    }
    __syncthreads();

    // per-row totals
    if (t < B_ROWS) {
        int s = 0;
        #pragma unroll
        for (int q = 0; q < NSEG; ++q) s += cur[t * NSEG + q];
        rowsum[t] = s;
        rowscan[t] = s;
    }
    __syncthreads();
    // inclusive scan over 128 rows
    for (int o = 1; o < B_ROWS; o <<= 1) {
        int u = 0;
        if (t < B_ROWS && t >= o) u = rowscan[t - o];
        __syncthreads();
        if (t < B_ROWS && t >= o) rowscan[t] += u;
        __syncthreads();
    }

    // per-row cursors + segoff emission
    if (t < B_ROWS) {
        int r = rbase + t;
        if (r < N_NODES) {
            int c0 = bbase[b] + rowscan[t] - rowsum[t];   // exclusive start
            #pragma unroll
            for (int q = 0; q < NSEG; ++q) {
                int c = cur[t * NSEG + q];
                cur[t * NSEG + q] = c0;
                segoff[r * SEGP1 + q] = c0;
                c0 += c;
            }
            segoff[r * SEGP1 + NSEG] = c0;
        }
    }
    __syncthreads();

    // pass 2: scatter into (row, seg)-ordered CSR
    for (int j = t; j < cnt; j += 256) {
        int2 eo = tmp[base + j];
        int rl = ((unsigned)eo.x) >> 25;
        int col = eo.x & 0x01FFFFFF;
        int p = atomicAdd(&cur[rl * NSEG + (col >> SEG_SHIFT)], 1);
        csr[p] = make_int2(col, eo.y);
    }
}

// ---------------------------------------------------------------------------
// Pass B (plain, middle path): per-row cursors (r4 version).
// ---------------------------------------------------------------------------
__global__ __launch_bounds__(256) void bucket_to_csr_kernel(
    const int* __restrict__ offsets, const int2* __restrict__ tmp,
    int2* __restrict__ csr) {
    __shared__ int lpos[B_ROWS];
    int b = blockIdx.x;
    int rbase = b << B_SHIFT;
    int t = threadIdx.x;
    if (t < B_ROWS) {
        int r = rbase + t;
        lpos[t] = offsets[(r < N_NODES) ? r : N_NODES];
    }
    __syncthreads();
    int start = offsets[rbase];
    int endr = rbase + B_ROWS;
    int end = offsets[(endr < N_NODES) ? endr : N_NODES];
    for (int j = start + t; j < end; j += 256) {
        int2 eo = tmp[j];
        int rl = ((unsigned)eo.x) >> 25;
        int col = eo.x & 0x01FFFFFF;
        int p = atomicAdd(&lpos[rl], 1);
        csr[p] = make_int2(col, eo.y);
    }
}

// ---------------------------------------------------------------------------
// Pull (r8 exact: persistent segment sweep, 4 rows/group, 1564 blocks,
// launch_bounds(256,8) -> all co-resident, lockstep seg sweep; 156us/305MB
// proven). r10's 3-row variant regressed (grid > residency -> tail; occ 49%).
// ---------------------------------------------------------------------------
__device__ __forceinline__ void h8_fma(uint4 u, float v, float* a) {
    __half2* hp = reinterpret_cast<__half2*>(&u);
    #pragma unroll
    for (int k = 0; k < 4; ++k) {
        float2 f = __half22float2(hp[k]);
        a[2 * k]     += v * f.x;
        a[2 * k + 1] += v * f.y;
    }
}

__global__ __launch_bounds__(256, 8) void pull_seg_kernel(
    const int* __restrict__ segoff, const int2* __restrict__ csr,
    const uint4* __restrict__ in16, float4* __restrict__ rep4,
    const float* __restrict__ mix) {
    int g = threadIdx.x >> 4;            // 0..15
    int l = threadIdx.x & 15;
    int r0 = blockIdx.x * 64 + g * 4;
    if (r0 >= N_NODES && (blockIdx.x * 64) >= N_NODES) return;
    float m0 = mix[0];
    float a[4][8];

    #pragma unroll
    for (int k = 0; k < 4; ++k) {
        int r = r0 + k;
        if (r < N_NODES) {
            uint4 xs = in16[(r << 4) | l];
            __half2* hp = reinterpret_cast<__half2*>(&xs);
            #pragma unroll
            for (int q = 0; q < 4; ++q) {
                float2 f = __half22float2(hp[q]);
                a[k][2 * q]     = m0 * f.x;
                a[k][2 * q + 1] = m0 * f.y;
            }
        }
    }

    int s0[4];
    #pragma unroll
    for (int k = 0; k < 4; ++k) {
        int r = r0 + k;
        s0[k] = (r < N_NODES) ? segoff[r * SEGP1] : 0;
    }

    for (int seg = 0; seg < NSEG; ++seg) {
        #pragma unroll
        for (int k = 0; k < 4; ++k) {
            int r = r0 + k;
            if (r >= N_NODES) continue;
            int s1 = segoff[r * SEGP1 + seg + 1];
            int j = s0[k];
            for (; j + 2 <= s1; j += 2) {
                int2 e0 = csr[j];
                int2 e1 = csr[j + 1];
                uint4 y0 = in16[(e0.x << 4) | l];
                uint4 y1 = in16[(e1.x << 4) | l];
                h8_fma(y0, __int_as_float(e0.y), a[k]);
                h8_fma(y1, __int_as_float(e1.y), a[k]);
            }
            if (j < s1) {
                int2 e = csr[j];
                uint4 y = in16[(e.x << 4) | l];
                h8_fma(y, __int_as_float(e.y), a[k]);
            }
            s0[k] = s1;
        }
    }

    #pragma unroll
    for (int k = 0; k < 4; ++k) {
        int r = r0 + k;
        if (r < N_NODES) {
            int o = (r << 5) | (l << 1);
            rep4[o]     = make_float4(a[k][0], a[k][1], a[k][2], a[k][3]);
            rep4[o + 1] = make_float4(a[k][4], a[k][5], a[k][6], a[k][7]);
        }
    }
}

// ---------------------------------------------------------------------------
// Pull (fp16 transient, middle path): r4 version.
// ---------------------------------------------------------------------------
__global__ __launch_bounds__(256) void pull16_kernel(
    const int* __restrict__ offsets, const int2* __restrict__ csr,
    const uint4* __restrict__ in16, float4* __restrict__ rep4,
    const float* __restrict__ mix) {
    int row = blockIdx.x * 16 + (threadIdx.x >> 4);
    int l = threadIdx.x & 15;
    if (row >= N_NODES) return;
    int j = offsets[row];
    int end = offsets[row + 1];
    float m0 = mix[0];
    float a[8];
    {
        uint4 xs = in16[(row << 4) | l];
        __half2* hp = reinterpret_cast<__half2*>(&xs);
        #pragma unroll
        for (int k = 0; k < 4; ++k) {
            float2 f = __half22float2(hp[k]);
            a[2 * k]     = m0 * f.x;
            a[2 * k + 1] = m0 * f.y;
        }
    }
    for (; j + 4 <= end; j += 4) {
        int2 e0 = csr[j + 0];
        int2 e1 = csr[j + 1];
        int2 e2 = csr[j + 2];
        int2 e3 = csr[j + 3];
        uint4 y0 = in16[(e0.x << 4) | l];
        uint4 y1 = in16[(e1.x << 4) | l];
        uint4 y2 = in16[(e2.x << 4) | l];
        uint4 y3 = in16[(e3.x << 4) | l];
        h8_fma(y0, __int_as_float(e0.y), a);
        h8_fma(y1, __int_as_float(e1.y), a);
        h8_fma(y2, __int_as_float(e2.y), a);
        h8_fma(y3, __int_as_float(e3.y), a);
    }
    for (; j < end; ++j) {
        int2 e = csr[j];
        uint4 y = in16[(e.x << 4) | l];
        h8_fma(y, __int_as_float(e.y), a);
    }
    int o = (row << 5) | (l << 1);
    rep4[o]     = make_float4(a[0], a[1], a[2], a[3]);
    rep4[o + 1] = make_float4(a[4], a[5], a[6], a[7]);
}

// ---------------------------------------------------------------------------
// Pull (f32, when ws can't hold input16)
// ---------------------------------------------------------------------------
__global__ __launch_bounds__(256) void pull_kernel(
    const int* __restrict__ offsets, const int2* __restrict__ csr,
    const float4* __restrict__ in4, float4* __restrict__ rep4,
    const float* __restrict__ mix) {
    int row = blockIdx.x * 8 + (threadIdx.x >> 5);
    int l = threadIdx.x & 31;
    if (row >= N_NODES) return;
    int j = offsets[row];
    int end = offsets[row + 1];
    float m0 = mix[0];
    float4 x = in4[(row << 5) | l];
    float4 acc = make_float4(m0 * x.x, m0 * x.y, m0 * x.z, m0 * x.w);
    for (; j + 1 < end; j += 2) {
        int2 e0 = csr[j];
        int2 e1 = csr[j + 1];
        float v0 = __int_as_float(e0.y);
        float v1 = __int_as_float(e1.y);
        float4 y0 = in4[(e0.x << 5) | l];
        float4 y1 = in4[(e1.x << 5) | l];
        acc.x += v0 * y0.x; acc.y += v0 * y0.y; acc.z += v0 * y0.z; acc.w += v0 * y0.w;
        acc.x += v1 * y1.x; acc.y += v1 * y1.y; acc.z += v1 * y1.z; acc.w += v1 * y1.w;
    }
    if (j < end) {
        int2 e0 = csr[j];
        float v0 = __int_as_float(e0.y);
        float4 y0 = in4[(e0.x << 5) | l];
        acc.x += v0 * y0.x; acc.y += v0 * y0.y; acc.z += v0 * y0.z; acc.w += v0 * y0.w;
    }
    rep4[(row << 5) | l] = acc;
}

// ---------------------------------------------------------------------------
// Fallback path (small ws): rep = mix[0]*input, then atomic push-scatter
// ---------------------------------------------------------------------------
__global__ __launch_bounds__(256) void rep_init_kernel(
    const float4* __restrict__ in4, float4* __restrict__ rep4,
    const float* __restrict__ mix) {
    int i = blockIdx.x * blockDim.x + threadIdx.x;
    if (i >= N_NODES * D / 4) return;
    float m0 = mix[0];
    float4 v = in4[i];
    v.x *= m0; v.y *= m0; v.z *= m0; v.w *= m0;
    rep4[i] = v;
}

__global__ __launch_bounds__(256) void scatter_kernel(
    const int* __restrict__ rows, const int* __restrict__ cols,
    const float* __restrict__ vals, const float4* __restrict__ in4,
    float* __restrict__ rep, const float* __restrict__ mix) {
    long long gid = (long long)blockIdx.x * blockDim.x + threadIdx.x;
    int e = (int)(gid >> 5);
    int l = (int)(gid & 31);
    if (e >= EDGES_TOTAL) return;
    int a = e / NNZ;
    int row = rows[e];
    int col = cols[e];
    float v = vals[e] * mix[a + 1];
    float4 x = in4[col * 32 + l];
    float* dst = rep + (long long)row * D + l * 4;
    atomicAdd(dst + 0, v * x.x);
    atomicAdd(dst + 1, v * x.y);
    atomicAdd(dst + 2, v * x.z);
    atomicAdd(dst + 3, v * x.w);
}

// ---------------------------------------------------------------------------
// out = rep @ W + bias. Register-blocked: 4 rows per thread (r4 win).
// ---------------------------------------------------------------------------
__global__ __launch_bounds__(256) void gemm_kernel(
    const float4* __restrict__ rep4, const float4* __restrict__ w4,
    const float4* __restrict__ bias4, float4* __restrict__ out4) {
    __shared__ float4 Wlds[D * (D / 4)];

    for (int idx = threadIdx.x; idx < D * (D / 4); idx += 256)
        Wlds[idx] = w4[idx];
    __syncthreads();

    int tc = threadIdx.x & 31;
    int rg = threadIdx.x >> 5;

    for (int base = blockIdx.x * 32; base < N_NODES; base += gridDim.x * 32) {
        int row0 = base + rg * 4;
        const float4* r0 = rep4 + (size_t)row0 * (D / 4);
        float4 acc0 = make_float4(0.f, 0.f, 0.f, 0.f);
        float4 acc1 = make_float4(0.f, 0.f, 0.f, 0.f);
        float4 acc2 = make_float4(0.f, 0.f, 0.f, 0.f);
        float4 acc3 = make_float4(0.f, 0.f, 0.f, 0.f);
        #pragma unroll 2
        for (int k4 = 0; k4 < D / 4; ++k4) {
            float4 a0 = r0[k4];
            float4 a1 = r0[(D / 4) + k4];
            float4 a2 = r0[2 * (D / 4) + k4];
            float4 a3 = r0[3 * (D / 4) + k4];
            float4 w0 = Wlds[(k4 * 4 + 0) * 32 + tc];
            float4 w1 = Wlds[(k4 * 4 + 1) * 32 + tc];
            float4 w2 = Wlds[(k4 * 4 + 2) * 32 + tc];
            float4 w3 = Wlds[(k4 * 4 + 3) * 32 + tc];
            acc0.x += a0.x * w0.x; acc0.y += a0.x * w0.y; acc0.z += a0.x * w0.z; acc0.w += a0.x * w0.w;
            acc0.x += a0.y * w1.x; acc0.y += a0.y * w1.y; acc0.z += a0.y * w1.z; acc0.w += a0.y * w1.w;
            acc0.x += a0.z * w2.x; acc0.y += a0.z * w2.y; acc0.z += a0.z * w2.z; acc0.w += a0.z * w2.w;
            acc0.x += a0.w * w3.x; acc0.y += a0.w * w3.y; acc0.z += a0.w * w3.z; acc0.w += a0.w * w3.w;
            acc1.x += a1.x * w0.x; acc1.y += a1.x * w0.y; acc1.z += a1.x * w0.z; acc1.w += a1.x * w0.w;
            acc1.x += a1.y * w1.x; acc1.y += a1.y * w1.y; acc1.z += a1.y * w1.z; acc1.w += a1.y * w1.w;
            acc1.x += a1.z * w2.x; acc1.y += a1.z * w2.y; acc1.z += a1.z * w2.z; acc1.w += a1.z * w2.w;
            acc1.x += a1.w * w3.x; acc1.y += a1.w * w3.y; acc1.z += a1.w * w3.z; acc1.w += a1.w * w3.w;
            acc2.x += a2.x * w0.x; acc2.y += a2.x * w0.y; acc2.z += a2.x * w0.z; acc2.w += a2.x * w0.w;
            acc2.x += a2.y * w1.x; acc2.y += a2.y * w1.y; acc2.z += a2.y * w1.z; acc2.w += a2.y * w1.w;
            acc2.x += a2.z * w2.x; acc2.y += a2.z * w2.y; acc2.z += a2.z * w2.z; acc2.w += a2.z * w2.w;
            acc2.x += a2.w * w3.x; acc2.y += a2.w * w3.y; acc2.z += a2.w * w3.z; acc2.w += a2.w * w3.w;
            acc3.x += a3.x * w0.x; acc3.y += a3.x * w0.y; acc3.z += a3.x * w0.z; acc3.w += a3.x * w0.w;
            acc3.x += a3.y * w1.x; acc3.y += a3.y * w1.y; acc3.z += a3.y * w1.z; acc3.w += a3.y * w1.w;
            acc3.x += a3.z * w2.x; acc3.y += a3.z * w2.y; acc3.z += a3.z * w2.z; acc3.w += a3.z * w2.w;
            acc3.x += a3.w * w3.x; acc3.y += a3.w * w3.y; acc3.z += a3.w * w3.z; acc3.w += a3.w * w3.w;
        }
        float4 b = bias4[tc];
        acc0.x += b.x; acc0.y += b.y; acc0.z += b.z; acc0.w += b.w;
        acc1.x += b.x; acc1.y += b.y; acc1.z += b.z; acc1.w += b.w;
        acc2.x += b.x; acc2.y += b.y; acc2.z += b.z; acc2.w += b.w;
        acc3.x += b.x; acc3.y += b.y; acc3.z += b.z; acc3.w += b.w;
        out4[(size_t)(row0 + 0) * (D / 4) + tc] = acc0;
        out4[(size_t)(row0 + 1) * (D / 4) + tc] = acc1;
        out4[(size_t)(row0 + 2) * (D / 4) + tc] = acc2;
        out4[(size_t)(row0 + 3) * (D / 4) + tc] = acc3;
    }
}

// ---------------------------------------------------------------------------
extern "C" void kernel_launch(void* const* d_in, const int* in_sizes, int n_in,
                              void* d_out, int out_size, void* d_ws, size_t ws_size,
                              hipStream_t stream) {
    const float* input         = (const float*)d_in[0];
    const int*   adj_rows      = (const int*)d_in[1];
    const int*   adj_cols      = (const int*)d_in[2];
    const float* adj_vals      = (const float*)d_in[3];
    const float* weight        = (const float*)d_in[4];
    const float* linear_weight = (const float*)d_in[5];
    const float* bias          = (const float*)d_in[6];

    float* out = (float*)d_out;                    // [N_NODES, D]
    float* rep = out + (size_t)N_NODES * D;        // [N_NODES, D]
    int2* tmp = (int2*)out;                        // 35.2MB <= 51.2MB alias

    // workspace layout
    char* ws = (char*)d_ws;
    float* mix      = (float*)ws;                        ws += 32;
    int*   counts   = (int*)ws;                          ws += sizeof(int) * N_NODES;
    int*   offsets  = (int*)ws;                          ws += sizeof(int) * (N_NODES + 4);
    int*   blockSums= (int*)ws;                          ws += sizeof(int) * 128;
    int*   bpos     = (int*)ws;                          ws += sizeof(int) * (NB + 2);
    int*   bbase    = (int*)ws;                          ws += sizeof(int) * (NB + 2);
    ws = (char*)(((uintptr_t)ws + 15) & ~(uintptr_t)15);
    int2*  csr      = (int2*)ws;                         ws += sizeof(int2) * EDGES_TOTAL;
    size_t needed1 = (size_t)(ws - (char*)d_ws);
    ws = (char*)(((uintptr_t)ws + 15) & ~(uintptr_t)15);
    uint4* input16  = (uint4*)ws;                        ws += sizeof(unsigned short) * (size_t)N_NODES * D;
    size_t needed2 = (size_t)(ws - (char*)d_ws);
    int*   segoff   = (int*)ws;                          ws += sizeof(int) * (size_t)N_NODES * SEGP1;
    size_t needed3 = (size_t)(ws - (char*)d_ws);

    softmax_mix_kernel<<<1, 64, 0, stream>>>(linear_weight, mix);

    if (ws_size >= needed1) {
        bool fp16path = (ws_size >= needed2);
        bool segpath  = (ws_size >= needed3);

        if (fp16path) {
            int total = N_NODES * D / 8;
            conv16_kernel<<<(total + 255) / 256, 256, 0, stream>>>(
                (const float4*)input, input16);
        }

        if (fp16path && segpath) {
            // ---- main path: fixed-cap buckets, seg-ordered CSR, seg pull --
            bpos_init_cap_kernel<<<(NB + 255) / 256, 256, 0, stream>>>(bpos);
            {
                int blocks = (EDGES_TOTAL + CHUNK - 1) / CHUNK;
                bucket_scatter_kernel<<<blocks, 256, 0, stream>>>(
                    adj_rows, adj_cols, adj_vals, mix, bpos, tmp);
            }
            bbase_scan_kernel<<<1, 256, 0, stream>>>(bpos, bbase);
            bucket_to_csr_seg2_kernel<<<NB, 256, 0, stream>>>(
                bpos, tmp, bbase, csr, segoff);
            pull_seg_kernel<<<PULL_BLOCKS, 256, 0, stream>>>(
                segoff, csr, input16, (float4*)rep, mix);
        } else {
            // ---- middle paths: original offsets-based pipeline ----
            hipMemsetAsync(counts, 0, sizeof(int) * N_NODES, stream);
            {
                int blocks = (EDGES_TOTAL + 255) / 256;
                hist_kernel<<<blocks, 256, 0, stream>>>(adj_rows, counts);
            }
            scan_partial_kernel<<<SCAN_BLOCKS, 256, 0, stream>>>(counts, blockSums);
            scan_blocksums_kernel<<<1, 64, 0, stream>>>(blockSums);
            scan_final_kernel<<<SCAN_BLOCKS, 256, 0, stream>>>(counts, blockSums, offsets);
            bpos_init_kernel<<<(NB + 255) / 256, 256, 0, stream>>>(offsets, bpos);
            {
                int blocks = (EDGES_TOTAL + CHUNK - 1) / CHUNK;
                bucket_scatter_kernel<<<blocks, 256, 0, stream>>>(
                    adj_rows, adj_cols, adj_vals, mix, bpos, tmp);
            }
            bucket_to_csr_kernel<<<NB, 256, 0, stream>>>(offsets, tmp, csr);
            if (fp16path) {
                int blocks = (N_NODES * 16 + 255) / 256;
                pull16_kernel<<<blocks, 256, 0, stream>>>(
                    offsets, csr, input16, (float4*)rep, mix);
            } else {
                long long threads = (long long)N_NODES * 32;
                int blocks = (int)((threads + 255) / 256);
                pull_kernel<<<blocks, 256, 0, stream>>>(
                    offsets, csr, (const float4*)input, (float4*)rep, mix);
            }
        }
    } else {
        {
            int total = N_NODES * D / 4;
            int blocks = (total + 255) / 256;
            rep_init_kernel<<<blocks, 256, 0, stream>>>(
                (const float4*)input, (float4*)rep, mix);
        }
        {
            long long threads = (long long)EDGES_TOTAL * 32;
            int blocks = (int)((threads + 255) / 256);
            scatter_kernel<<<blocks, 256, 0, stream>>>(
                adj_rows, adj_cols, adj_vals, (const float4*)input, rep, mix);
        }
    }

    gemm_kernel<<<2048, 256, 0, stream>>>(
        (const float4*)rep, (const float4*)weight,
        (const float4*)bias, (float4*)out);
}